// Round 6
// baseline (229.983 us; speedup 1.0000x reference)
//
#include <hip/hip_runtime.h>
#include <math.h>

#define BB 16
#define PP 4096
#define TT 1024
#define PCAP 1536          // pred bucket capacity per (b,c): 1024 + 18 sigma
#define TCAP 384           // target bucket capacity per (b,c): 256 + 9 sigma
#define CHUNKS 48          // TCAP / 8 target-chunks per (b,c)
#define LIMKEY 0x41C80FFFu // key <= this  <=>  quantized d2 <= 25.0f (bits 0x41C80000)

// Phase 1: scatter preds and targets into per-(batch,class) buckets.
// Grid 64 = 16 b x 4 quarters; global atomic slot allocation (order
// nondeterminism is harmless: keys carry the original pred index).
__global__ __launch_bounds__(256) void build_kernel(const float* __restrict__ pred,
                                                    const float* __restrict__ gt,
                                                    float* __restrict__ pred_x,
                                                    float* __restrict__ pred_y,
                                                    unsigned* __restrict__ pred_po,
                                                    float* __restrict__ tgt_x,
                                                    float* __restrict__ tgt_y,
                                                    int* __restrict__ cnt_p,
                                                    int* __restrict__ cnt_t) {
    const int b = blockIdx.x >> 2;
    const int q = blockIdx.x & 3;
    #pragma unroll
    for (int i = 0; i < 4; ++i) {
        const int p = q * 1024 + i * 256 + threadIdx.x;
        const float* pp = pred + ((size_t)b * PP + p) * 3;
        const float cls = pp[0], x = pp[1], y = pp[2];
        const int bc = b * 4 + (int)cls;
        const int slot = atomicAdd(&cnt_p[bc], 1);
        if (slot < PCAP) {
            pred_x[bc * PCAP + slot]  = x;
            pred_y[bc * PCAP + slot]  = y;
            pred_po[bc * PCAP + slot] = (unsigned)p;
        }
    }
    const int t = q * 256 + threadIdx.x;
    const float* tp_ = gt + ((size_t)b * TT + t) * 3;
    const float cls = tp_[0], x = tp_[1], y = tp_[2];
    const int bc = b * 4 + (int)cls;
    const int slot = atomicAdd(&cnt_t[bc], 1);
    if (slot < TCAP) {
        tgt_x[bc * TCAP + slot] = x;
        tgt_y[bc * TCAP + slot] = y;
    }
}

// Phase 2: each wave owns 8 same-class targets and scans its (b,c) pred
// bucket. Per pair: sub,sub,mul,fma,and,or,v_min_u32 = 7 ops. Packed key
// (d2_bits & ~0xFFF) | orig_p gives argmin + lowest-p tie-break via plain
// u32 min. Radius test deferred to count_kernel. part slot written for
// every real target -> no init needed.
__global__ __launch_bounds__(256) void match_kernel(const float* __restrict__ pred_x,
                                                    const float* __restrict__ pred_y,
                                                    const unsigned* __restrict__ pred_po,
                                                    const float* __restrict__ tgt_x,
                                                    const float* __restrict__ tgt_y,
                                                    const int* __restrict__ cnt_p,
                                                    const int* __restrict__ cnt_t,
                                                    unsigned* __restrict__ part) {
    const int wgid  = blockIdx.x * 4 + (threadIdx.x >> 6);  // 0..3071
    const int bc    = wgid / CHUNKS;
    const int chunk = wgid - bc * CHUNKS;
    const int lane  = threadIdx.x & 63;

    const int ct = cnt_t[bc];
    const int tstart = chunk * 8;
    if (tstart >= ct) return;   // wave-uniform, no barriers in this kernel

    const int tb = bc * TCAP + tstart;
    float gx[8], gy[8];
    unsigned key[8];
    #pragma unroll
    for (int j = 0; j < 8; ++j) {
        gx[j] = tgt_x[tb + j];   // slots >= ct hold ws poison (finite) - unused
        gy[j] = tgt_y[tb + j];
        key[j] = 0xFFFFFFFFu;
    }

    const int cp = cnt_p[bc];
    const int npad = (cp + 63) & ~63;   // <= PCAP, so loads stay in-plane
    const int pb = bc * PCAP;
    for (int i = 0; i < npad; i += 64) {
        const int slot = i + lane;
        float px = pred_x[pb + slot];
        const float py = pred_y[pb + slot];
        const unsigned po = pred_po[pb + slot];
        px = (slot < cp) ? px : 1.0e9f;   // pad lanes -> huge d2, radius-rejected
        #pragma unroll
        for (int j = 0; j < 8; ++j) {
            const float dx = px - gx[j];
            const float dy = py - gy[j];
            const float d2 = fmaf(dx, dx, dy * dy);
            const unsigned kk = (__float_as_uint(d2) & 0xFFFFF000u) | po;
            key[j] = min(key[j], kk);
        }
    }

    for (int off = 32; off; off >>= 1) {
        #pragma unroll
        for (int j = 0; j < 8; ++j) {
            const unsigned o = __shfl_down(key[j], off, 64);
            key[j] = min(key[j], o);
        }
    }

    if (lane == 0) {
        const int nact = min(8, ct - tstart);
        for (int j = 0; j < nact; ++j)
            part[bc * TCAP + tstart + j] = key[j];
    }
}

// Phase 3: per-batch block: radius-filter keys, bitmap distinct hit preds,
// popcount -> partial tp.
__global__ __launch_bounds__(256) void count_kernel(const unsigned* __restrict__ part,
                                                    const int* __restrict__ cnt_t,
                                                    int* __restrict__ psum) {
    __shared__ unsigned bm[PP / 32];   // 128 words
    if (threadIdx.x < 128) bm[threadIdx.x] = 0;
    __syncthreads();
    const int b = blockIdx.x;
    for (int c = 0; c < 4; ++c) {
        const int bc = b * 4 + c;
        const int ct = cnt_t[bc];
        for (int s = threadIdx.x; s < ct; s += 256) {
            const unsigned k = part[bc * TCAP + s];
            if (k <= LIMKEY) {
                const unsigned p = k & 0xFFFu;
                atomicOr(&bm[p >> 5], 1u << (p & 31));
            }
        }
    }
    __syncthreads();
    int sum = (threadIdx.x < 128) ? (int)__popc(bm[threadIdx.x]) : 0;
    for (int off = 32; off; off >>= 1) sum += __shfl_down(sum, off, 64);
    __shared__ int ss[4];
    if ((threadIdx.x & 63) == 0) ss[threadIdx.x >> 6] = sum;
    __syncthreads();
    if (threadIdx.x == 0) psum[b] = ss[0] + ss[1] + ss[2] + ss[3];
}

// Phase 4: one wave: sum partials, F1 scalar.
__global__ void f1_kernel(const int* __restrict__ psum, float* __restrict__ out) {
    int v = (threadIdx.x < BB) ? psum[threadIdx.x] : 0;
    for (int off = 32; off; off >>= 1) v += __shfl_down(v, off, 64);
    if (threadIdx.x == 0) {
        const float tp = (float)v;
        const float eps = 1e-6f;
        const float fp = (float)(BB * PP) - tp;
        const float fn = (float)(BB * TT) - tp;
        const float precision = (tp + eps) / (tp + eps + fp + eps);
        const float recall    = (tp + eps) / (tp + fn + eps);
        const float f1 = 2.0f * precision * recall / (precision + recall);
        out[0] = 1.0f - f1;
    }
}

extern "C" void kernel_launch(void* const* d_in, const int* in_sizes, int n_in,
                              void* d_out, int out_size, void* d_ws, size_t ws_size,
                              hipStream_t stream) {
    const float* pred = (const float*)d_in[0];  // (B, P, 3): cls, x, y
    const float* gt   = (const float*)d_in[1];  // (B, T, 3)
    float* out = (float*)d_out;

    char* ws = (char*)d_ws;
    float*    pred_x  = (float*)   (ws + 0);        // 64*1536*4 = 393216
    float*    pred_y  = (float*)   (ws + 393216);
    unsigned* pred_po = (unsigned*)(ws + 786432);
    float*    tgt_x   = (float*)   (ws + 1179648);  // 64*384*4 = 98304
    float*    tgt_y   = (float*)   (ws + 1277952);
    int*      cnt_p   = (int*)     (ws + 1376256);  // 256 B
    int*      cnt_t   = (int*)     (ws + 1376512);  // 256 B
    unsigned* part    = (unsigned*)(ws + 1376768);  // 64*384*4 = 98304
    int*      psum    = (int*)     (ws + 1475072);  // 64 B

    hipMemsetAsync(cnt_p, 0, 512, stream);          // cnt_p + cnt_t
    build_kernel<<<64, 256, 0, stream>>>(pred, gt, pred_x, pred_y, pred_po,
                                         tgt_x, tgt_y, cnt_p, cnt_t);
    match_kernel<<<16 * 4 * CHUNKS / 4, 256, 0, stream>>>(pred_x, pred_y, pred_po,
                                                          tgt_x, tgt_y, cnt_p, cnt_t, part);
    count_kernel<<<BB, 256, 0, stream>>>(part, cnt_t, psum);
    f1_kernel<<<1, 64, 0, stream>>>(psum, out);
}

// Round 7
// 73.503 us; speedup vs baseline: 3.1289x; 3.1289x over previous
//
#include <hip/hip_runtime.h>
#include <math.h>

#define BB 16
#define PP 4096
#define TT 1024
#define JT 8
#define HALF 2048          // preds per block (P split in 2)
#define LIMKEY 0x41C80FFFu // key <= this  <=>  quantized d2 <= 25.0f (0x41C80000)

// Grid: 1024 blocks = 16 b x 32 target-tiles x 2 P-halves. Block = 256 thr = 4 waves.
// Class-island encoding: x' = fma(cls, 128, x). Same-class d2 preserved to ~1e-3;
// cross-class d2 >= 4096 -> auto-rejected by deferred radius test (d2<=25), so no
// per-pair class compare. Packed key (d2_bits & ~0xFFF) | p gives argmin + lowest-p
// tie-break via one v_min_u32; inner loop = 6 VALU/pair.
// part[half][b*TT+t] fully written -> no ws zero-init.
__global__ __launch_bounds__(256) void match_kernel(const float* __restrict__ pred,
                                                    const float* __restrict__ gt,
                                                    unsigned* __restrict__ part) {
    const int blk   = blockIdx.x;
    const int b     = blk >> 6;          // 64 blocks per batch
    const int ttile = (blk >> 1) & 31;   // 32 targets per block
    const int half  = blk & 1;
    const int wave  = threadIdx.x >> 6;  // 0..3
    const int lane  = threadIdx.x & 63;
    const int tbase = ttile * 32 + wave * JT;
    const int pbase = half * HALF;

    const float* gb = gt + ((size_t)(b * TT + tbase)) * 3;
    float gx[JT], gy[JT];
    unsigned key[JT];
    #pragma unroll
    for (int j = 0; j < JT; ++j) {
        const float c = gb[j * 3 + 0];
        gx[j] = fmaf(c, 128.0f, gb[j * 3 + 1]);   // island offset by class
        gy[j] = gb[j * 3 + 2];
        key[j] = 0xFFFFFFFFu;
    }

    const float* pl = pred + (size_t)b * PP * 3 + (size_t)(pbase + lane) * 3;

    #pragma unroll 4
    for (int i = 0; i < HALF / 64; ++i) {
        const float pc = pl[0];
        const float px = pl[1];
        const float py = pl[2];
        pl += 192;
        const float pxp = fmaf(pc, 128.0f, px);
        const unsigned po = (unsigned)(pbase + (i << 6) + lane);
        #pragma unroll
        for (int j = 0; j < JT; ++j) {
            const float dx = pxp - gx[j];
            const float dy = py - gy[j];
            const float d2 = fmaf(dx, dx, dy * dy);
            const unsigned kk = (__float_as_uint(d2) & 0xFFFFF000u) | po;
            key[j] = min(key[j], kk);
        }
    }

    for (int off = 32; off; off >>= 1) {
        #pragma unroll
        for (int j = 0; j < JT; ++j) {
            const unsigned o = __shfl_down(key[j], off, 64);
            key[j] = min(key[j], o);
        }
    }

    if (lane == 0) {
        #pragma unroll
        for (int j = 0; j < JT; ++j)
            part[(size_t)half * (BB * TT) + b * TT + tbase + j] = key[j];
    }
}

// Single block: min-combine the 2 P-halves per target, radius-filter, bitmap
// distinct hit preds in 8KB LDS, popcount -> tp, F1 scalar.
__global__ __launch_bounds__(1024) void count_kernel(const unsigned* __restrict__ part,
                                                     float* __restrict__ out) {
    __shared__ unsigned bm[BB * PP / 32];   // 2048 words
    for (int i = threadIdx.x; i < BB * PP / 32; i += 1024) bm[i] = 0;
    __syncthreads();

    for (int i = threadIdx.x; i < BB * TT; i += 1024) {
        const unsigned k = min(part[i], part[BB * TT + i]);
        if (k <= LIMKEY) {
            const unsigned g = (unsigned)(i >> 10) * PP + (k & 0xFFFu);
            atomicOr(&bm[g >> 5], 1u << (g & 31));
        }
    }
    __syncthreads();

    int sum = 0;
    for (int i = threadIdx.x; i < BB * PP / 32; i += 1024) sum += __popc(bm[i]);
    for (int off = 32; off; off >>= 1) sum += __shfl_down(sum, off, 64);

    __shared__ int ss[16];
    const int wid  = threadIdx.x >> 6;
    const int lane = threadIdx.x & 63;
    if (lane == 0) ss[wid] = sum;
    __syncthreads();
    if (threadIdx.x == 0) {
        int tp_i = 0;
        for (int w = 0; w < 16; ++w) tp_i += ss[w];
        const float tp = (float)tp_i;
        const float eps = 1e-6f;
        const float fp = (float)(BB * PP) - tp;
        const float fn = (float)(BB * TT) - tp;
        const float precision = (tp + eps) / (tp + eps + fp + eps);
        const float recall    = (tp + eps) / (tp + fn + eps);
        const float f1 = 2.0f * precision * recall / (precision + recall);
        out[0] = 1.0f - f1;
    }
}

extern "C" void kernel_launch(void* const* d_in, const int* in_sizes, int n_in,
                              void* d_out, int out_size, void* d_ws, size_t ws_size,
                              hipStream_t stream) {
    const float* pred = (const float*)d_in[0];  // (B, P, 3): cls, x, y
    const float* gt   = (const float*)d_in[1];  // (B, T, 3)
    float* out = (float*)d_out;
    unsigned* part = (unsigned*)d_ws;           // 2 * B*T u32 = 128 KB

    match_kernel<<<BB * TT / 32 * 2, 256, 0, stream>>>(pred, gt, part);
    count_kernel<<<1, 1024, 0, stream>>>(part, out);
}

// Round 8
// 71.138 us; speedup vs baseline: 3.2329x; 1.0333x over previous
//
#include <hip/hip_runtime.h>
#include <math.h>

#define BB 16
#define PP 4096
#define TT 1024
#define JT 16
#define QTR 1024           // preds per block (P split in 4 quarters)
#define LIMKEY 0x41C80FFFu // key <= this  <=>  quantized d2 <= 25.0f (0x41C80000)

// Grid: 1024 blocks = 16 b x 16 target-tiles x 4 P-quarters. Block = 256 thr = 4 waves.
// Each wave owns 16 targets, scans its 1024-pred quarter (lane = p mod 64).
// Class-island encoding: x' = fma(cls, 128, x) -> cross-class d2 >= 4096, auto-
// rejected by deferred radius test; no per-pair class compare. Packed key
// (d2_bits & ~0xFFF) | p gives argmin + lowest-p tie-break via one v_min_u32.
// Inner loop = 6 VALU/pair, 3 loads amortized over 16 targets.
// part[quarter][b*TT+t] fully written -> no ws zero-init.
__global__ __launch_bounds__(256) void match_kernel(const float* __restrict__ pred,
                                                    const float* __restrict__ gt,
                                                    unsigned* __restrict__ part) {
    const int blk   = blockIdx.x;
    const int b     = blk >> 6;           // 64 blocks per batch
    const int ttile = (blk >> 2) & 15;    // 64 targets per block
    const int qtr   = blk & 3;
    const int wave  = threadIdx.x >> 6;   // 0..3
    const int lane  = threadIdx.x & 63;
    const int tbase = ttile * 64 + wave * JT;
    const int pbase = qtr * QTR;

    const float* gb = gt + ((size_t)(b * TT + tbase)) * 3;
    float gx[JT], gy[JT];
    unsigned key[JT];
    #pragma unroll
    for (int j = 0; j < JT; ++j) {
        const float c = gb[j * 3 + 0];
        gx[j] = fmaf(c, 128.0f, gb[j * 3 + 1]);   // island offset by class
        gy[j] = gb[j * 3 + 2];
        key[j] = 0xFFFFFFFFu;
    }

    const float* pl = pred + (size_t)b * PP * 3 + (size_t)(pbase + lane) * 3;

    #pragma unroll 4
    for (int i = 0; i < QTR / 64; ++i) {
        const float pc = pl[0];
        const float px = pl[1];
        const float py = pl[2];
        pl += 192;
        const float pxp = fmaf(pc, 128.0f, px);
        const unsigned po = (unsigned)(pbase + (i << 6) + lane);
        #pragma unroll
        for (int j = 0; j < JT; ++j) {
            const float dx = pxp - gx[j];
            const float dy = py - gy[j];
            const float d2 = fmaf(dx, dx, dy * dy);
            const unsigned kk = (__float_as_uint(d2) & 0xFFFFF000u) | po;
            key[j] = min(key[j], kk);
        }
    }

    for (int off = 32; off; off >>= 1) {
        #pragma unroll
        for (int j = 0; j < JT; ++j) {
            const unsigned o = __shfl_down(key[j], off, 64);
            key[j] = min(key[j], o);
        }
    }

    if (lane == 0) {
        #pragma unroll
        for (int j = 0; j < JT; ++j)
            part[(size_t)qtr * (BB * TT) + b * TT + tbase + j] = key[j];
    }
}

// 16 blocks (one per batch): min-combine 4 quarters per target, radius-filter,
// bitmap distinct hit preds in 512B LDS, popcount -> psum[b].
__global__ __launch_bounds__(256) void count_kernel(const unsigned* __restrict__ part,
                                                    int* __restrict__ psum) {
    __shared__ unsigned bm[PP / 32];   // 128 words
    if (threadIdx.x < 128) bm[threadIdx.x] = 0;
    __syncthreads();

    const int b = blockIdx.x;
    const unsigned* pb = part + b * TT;
    for (int i = threadIdx.x; i < TT; i += 256) {
        unsigned k = min(min(pb[i], pb[BB * TT + i]),
                         min(pb[2 * BB * TT + i], pb[3 * BB * TT + i]));
        if (k <= LIMKEY) {
            const unsigned p = k & 0xFFFu;
            atomicOr(&bm[p >> 5], 1u << (p & 31));
        }
    }
    __syncthreads();

    int sum = (threadIdx.x < 128) ? (int)__popc(bm[threadIdx.x]) : 0;
    for (int off = 32; off; off >>= 1) sum += __shfl_down(sum, off, 64);
    __shared__ int ss[4];
    if ((threadIdx.x & 63) == 0) ss[threadIdx.x >> 6] = sum;
    __syncthreads();
    if (threadIdx.x == 0) psum[b] = ss[0] + ss[1] + ss[2] + ss[3];
}

// One wave: sum the 16 partials, F1 scalar.
__global__ void f1_kernel(const int* __restrict__ psum, float* __restrict__ out) {
    int v = (threadIdx.x < BB) ? psum[threadIdx.x] : 0;
    for (int off = 32; off; off >>= 1) v += __shfl_down(v, off, 64);
    if (threadIdx.x == 0) {
        const float tp = (float)v;
        const float eps = 1e-6f;
        const float fp = (float)(BB * PP) - tp;
        const float fn = (float)(BB * TT) - tp;
        const float precision = (tp + eps) / (tp + eps + fp + eps);
        const float recall    = (tp + eps) / (tp + fn + eps);
        const float f1 = 2.0f * precision * recall / (precision + recall);
        out[0] = 1.0f - f1;
    }
}

extern "C" void kernel_launch(void* const* d_in, const int* in_sizes, int n_in,
                              void* d_out, int out_size, void* d_ws, size_t ws_size,
                              hipStream_t stream) {
    const float* pred = (const float*)d_in[0];  // (B, P, 3): cls, x, y
    const float* gt   = (const float*)d_in[1];  // (B, T, 3)
    float* out = (float*)d_out;

    unsigned* part = (unsigned*)d_ws;                     // 4 * B*T u32 = 256 KB
    int* psum = (int*)((char*)d_ws + 4 * BB * TT * 4);    // 16 ints, always written

    match_kernel<<<BB * 16 * 4, 256, 0, stream>>>(pred, gt, part);
    count_kernel<<<BB, 256, 0, stream>>>(part, psum);
    f1_kernel<<<1, 64, 0, stream>>>(psum, out);
}